// Round 5
// baseline (699.163 us; speedup 1.0000x reference)
//
#include <hip/hip_runtime.h>

// ABLATION ROUND. Multihead self-attention w/ 3-scale relative embeddings.
// B=4, S=1024, D=512, H=8, HD=64.
// Seven attn variants dispatched back-to-back; rocprof separates them.
// V5: write-path only | V4: no PV/out | V3: no K loads | V2: no Er loads
// V1: no attn store   | V0: full (round-4 order) | V6: full, attn store LAST.
// V6 runs last => final d_out state is correct.

typedef float f32x4 __attribute__((ext_vector_type(4)));
typedef short s16x8 __attribute__((ext_vector_type(8)));
typedef short s16x4 __attribute__((ext_vector_type(4)));
typedef __bf16 bf16x8 __attribute__((ext_vector_type(8)));

static __device__ __forceinline__ short f2bf(float f) {
    return __builtin_bit_cast(short, (__bf16)f);
}
static __device__ __forceinline__ float bf2f(short s) {
    union { unsigned u; float f; } v;
    v.u = ((unsigned)(unsigned short)s) << 16;
    return v.f;
}
static __device__ __forceinline__ f32x4 MM(s16x8 a, s16x8 b, f32x4 c) {
    return __builtin_amdgcn_mfma_f32_16x16x32_bf16(
        __builtin_bit_cast(bf16x8, a), __builtin_bit_cast(bf16x8, b), c, 0, 0, 0);
}
#define SINK4(x) asm volatile("" :: "v"(x))

// ---------------------------------------------------------------------------
struct CvtArgs {
    const float* src[9];
    short* dst[9];
    unsigned n[9];
};

__global__ __launch_bounds__(256) void convert_kernel(CvtArgs a) {
    const int ai = blockIdx.y;
    const unsigned n = a.n[ai];
    const float* __restrict__ s = a.src[ai];
    short* __restrict__ d = a.dst[ai];
    const unsigned stride = gridDim.x * 256 * 8;
    for (unsigned base = (blockIdx.x * 256 + threadIdx.x) * 8; base < n; base += stride) {
        f32x4 v0 = *(const f32x4*)(s + base);
        f32x4 v1 = *(const f32x4*)(s + base + 4);
        s16x8 o;
        o[0] = f2bf(v0[0]); o[1] = f2bf(v0[1]); o[2] = f2bf(v0[2]); o[3] = f2bf(v0[3]);
        o[4] = f2bf(v1[0]); o[5] = f2bf(v1[1]); o[6] = f2bf(v1[2]); o[7] = f2bf(v1[3]);
        *(s16x8*)(d + base) = o;
    }
}

// ---------------------------------------------------------------------------
__global__ __launch_bounds__(256, 2) void proj_kernel(
    const short* __restrict__ queryb, const short* __restrict__ keyb, const short* __restrict__ valueb,
    const short* __restrict__ Wqb, const float* __restrict__ bq,
    const short* __restrict__ Wkb, const float* __restrict__ bk,
    const short* __restrict__ Wvb, const float* __restrict__ bv,
    short* __restrict__ qb, short* __restrict__ kb, short* __restrict__ vT)
{
    const int tid = threadIdx.x;
    const int wid = tid >> 6, lane = tid & 63;
    const int l15 = lane & 15, grp = lane >> 4;
    const int gid = blockIdx.x * 4 + wid;
    const int z = gid >> 11;
    const int r = gid & 2047;

    const short *Am, *Bm;
    const float* bias;
    int a0, b0;
    if (z == 0)      { Am = queryb; Bm = Wqb;    bias = bq; a0 = (r >> 4) * 32; b0 = (r & 15) * 32; }
    else if (z == 1) { Am = keyb;   Bm = Wkb;    bias = bk; a0 = (r >> 4) * 32; b0 = (r & 15) * 32; }
    else             { Am = Wvb;    Bm = valueb; bias = bv; a0 = (r >> 7) * 32; b0 = (r & 127) * 32; }

    f32x4 acc[2][2];
    #pragma unroll
    for (int i = 0; i < 2; ++i)
        #pragma unroll
        for (int j = 0; j < 2; ++j)
            acc[i][j] = f32x4{0.f, 0.f, 0.f, 0.f};

    const short* arow0 = Am + (size_t)(a0 + l15) * 512 + grp * 8;
    const short* brow0 = Bm + (size_t)(b0 + l15) * 512 + grp * 8;

    s16x8 aA[2], bA[2], aB[2], bB[2], aC[2], bC[2];
    #pragma unroll
    for (int i = 0; i < 2; ++i) {
        aA[i] = *(const s16x8*)(arow0 + (size_t)i * 16 * 512);
        bA[i] = *(const s16x8*)(brow0 + (size_t)i * 16 * 512);
        aB[i] = *(const s16x8*)(arow0 + (size_t)i * 16 * 512 + 32);
        bB[i] = *(const s16x8*)(brow0 + (size_t)i * 16 * 512 + 32);
        aC[i] = *(const s16x8*)(arow0 + (size_t)i * 16 * 512 + 64);
        bC[i] = *(const s16x8*)(brow0 + (size_t)i * 16 * 512 + 64);
    }
    for (int kk = 0; kk < 512; kk += 32) {
        #pragma unroll
        for (int i = 0; i < 2; ++i)
            #pragma unroll
            for (int j = 0; j < 2; ++j)
                acc[i][j] = MM(aA[i], bA[j], acc[i][j]);
        #pragma unroll
        for (int i = 0; i < 2; ++i) { aA[i] = aB[i]; bA[i] = bB[i]; aB[i] = aC[i]; bB[i] = bC[i]; }
        const int kn = kk + 96;
        if (kn < 512) {
            #pragma unroll
            for (int i = 0; i < 2; ++i) {
                aC[i] = *(const s16x8*)(arow0 + (size_t)i * 16 * 512 + kn);
                bC[i] = *(const s16x8*)(brow0 + (size_t)i * 16 * 512 + kn);
            }
        }
    }

    if (z < 2) {
        short* dst = (z == 0) ? qb : kb;
        #pragma unroll
        for (int j = 0; j < 2; ++j) {
            const int n = b0 + j * 16 + l15;
            const float bval = bias[n];
            const int h = n >> 6, d = n & 63;
            #pragma unroll
            for (int i = 0; i < 2; ++i)
                #pragma unroll
                for (int g = 0; g < 4; ++g) {
                    const int m = a0 + i * 16 + grp * 4 + g;
                    const int bb = m >> 10, s = m & 1023;
                    dst[(size_t)((bb * 8 + h) * 1024 + s) * 64 + d] = f2bf(acc[i][j][g] + bval);
                }
        }
    } else {
        #pragma unroll
        for (int i = 0; i < 2; ++i)
            #pragma unroll
            for (int g = 0; g < 4; ++g) {
                const int n = a0 + i * 16 + grp * 4 + g;
                const float bval = bias[n];
                const int h = n >> 6, d = n & 63;
                #pragma unroll
                for (int j = 0; j < 2; ++j) {
                    const int m = b0 + j * 16 + l15;
                    const int bb = m >> 10, s = m & 1023;
                    vT[(size_t)((bb * 8 + h) * 64 + d) * 1024 + s] = f2bf(acc[i][j][g] + bval);
                }
            }
    }
}

// ---------------------------------------------------------------------------
// attn ablation kernel.  Gates:
//  P1: phase1 tables | ERL: Er global loads | KL: K global loads
//  QKT: loop1+sums   | PVx: V loads+PV+out  | AST: attn store | LAST: store at end
// ---------------------------------------------------------------------------
template<int V>
__global__ __launch_bounds__(512, 2) void attn_ab(
    const short* __restrict__ Eqb, const short* __restrict__ Ebb, const short* __restrict__ Errb,
    const short* __restrict__ qb, const short* __restrict__ kb, const short* __restrict__ vT,
    float* __restrict__ out, float* __restrict__ attn)
{
    constexpr bool P1   = (V != 5);
    constexpr bool ERL  = (V != 2) && P1;
    constexpr bool KL   = (V != 3) && (V != 5);
    constexpr bool QKT  = (V != 5);
    constexpr bool PVx  = (V != 4) && (V != 5);
    constexpr bool AST  = (V != 1);
    constexpr bool LAST = (V == 6);

    __shared__ __align__(16) char smem[44416];
    short* RQ   = (short*)smem;                 // [16][1048]
    short* PS   = (short*)smem;                 // [16][1032] (reuse)
    short* RBT  = (short*)(smem + 33536);       // [260][16]
    float* PACC = (float*)(smem + 33536);       // [8][16][16] (reuse of RBT)
    short* RRT  = (short*)(smem + 41856);       // [64][16]
    float* RSUM = (float*)(smem + 43904);       // [16][8]
    const int RQS = 1048, PSS = 1032;

    const int tid = threadIdx.x;
    const int wid = tid >> 6, lane = tid & 63;
    const int l15 = lane & 15, grp = lane >> 4;

    const int orig = blockIdx.x;
    const int bid = (orig & 7) * (2048 >> 3) + (orig >> 3);

    const int bh = bid >> 6;
    const int i0 = (bid & 63) << 4;
    const int h = bh & 7;

    const short* EqH = Eqb  + (size_t)h * 2047 * 64;
    const short* EbH = Ebb  + (size_t)h * 511 * 64;
    const short* ErH = Errb + (size_t)h * 127 * 64;
    const short* qbH = qb + (size_t)bh * 1024 * 64;
    const short* kbH = kb + (size_t)bh * 1024 * 64;
    const short* vTH = vT + (size_t)bh * 64 * 1024;

    s16x8 qfr[2];
    #pragma unroll
    for (int kh = 0; kh < 2; ++kh)
        qfr[kh] = *(const s16x8*)(qbH + (size_t)(i0 + l15) * 64 + kh * 32 + grp * 8);

    s16x8 kf[8][2];
    if constexpr (KL) {
        #pragma unroll
        for (int t = 0; t < 8; ++t) {
            const short* kp = kbH + (size_t)(wid * 128 + t * 16 + l15) * 64 + grp * 8;
            kf[t][0] = *(const s16x8*)kp;
            kf[t][1] = *(const s16x8*)(kp + 32);
        }
    } else {
        #pragma unroll
        for (int t = 0; t < 8; ++t) { kf[t][0] = qfr[0]; kf[t][1] = qfr[1]; }
    }

    if constexpr (P1) {
        const int qbase = 1008 - i0;
        for (int cs = wid; cs < 65; cs += 8) {
            s16x8 e0, e1;
            if constexpr (ERL) {
                int erow = qbase + cs * 16 + l15; if (erow > 2046) erow = 2046;
                const short* ep = EqH + (size_t)erow * 64 + grp * 8;
                e0 = *(const s16x8*)ep;
                e1 = *(const s16x8*)(ep + 32);
            } else { e0 = qfr[0]; e1 = qfr[1]; }
            f32x4 a = f32x4{0.f, 0.f, 0.f, 0.f};
            a = MM(qfr[0], e0, a);
            a = MM(qfr[1], e1, a);
            #pragma unroll
            for (int g = 0; g < 4; ++g)
                RQ[(grp * 4 + g) * RQS + cs * 16 + l15] = f2bf(a[g]);
        }
        const int bbase = 252 - (i0 >> 2);
        for (int cs = wid; cs < 17; cs += 8) {
            s16x8 e0, e1;
            if constexpr (ERL) {
                int erow = bbase + cs * 16 + l15; if (erow > 510) erow = 510;
                const short* ep = EbH + (size_t)erow * 64 + grp * 8;
                e0 = *(const s16x8*)ep;
                e1 = *(const s16x8*)(ep + 32);
            } else { e0 = qfr[0]; e1 = qfr[1]; }
            f32x4 a = f32x4{0.f, 0.f, 0.f, 0.f};
            a = MM(qfr[0], e0, a);
            a = MM(qfr[1], e1, a);
            const int c = cs * 16 + l15;
            if (c < 260) {
                #pragma unroll
                for (int g = 0; g < 4; ++g)
                    RBT[c * 16 + grp * 4 + g] = f2bf(a[g]);
            }
        }
        const int rbase = 63 - (i0 >> 4);
        if (wid < 4) {
            s16x8 e0, e1;
            if constexpr (ERL) {
                const int erow = rbase + wid * 16 + l15;
                const short* ep = ErH + (size_t)erow * 64 + grp * 8;
                e0 = *(const s16x8*)ep;
                e1 = *(const s16x8*)(ep + 32);
            } else { e0 = qfr[0]; e1 = qfr[1]; }
            f32x4 a = f32x4{0.f, 0.f, 0.f, 0.f};
            a = MM(qfr[0], e0, a);
            a = MM(qfr[1], e1, a);
            #pragma unroll
            for (int g = 0; g < 4; ++g)
                RRT[(wid * 16 + l15) * 16 + grp * 4 + g] = f2bf(a[g]);
        }
        __syncthreads();
    }

    // ---- loop 1 / p values ----
    const float SC = 0.125f * 1.4426950408889634f;
    f32x4 p[8];
    float rinv[4];
    if constexpr (QKT) {
        #pragma unroll
        for (int t = 0; t < 8; ++t) {
            const int jb = wid * 128 + t * 16;
            const int j = jb + l15;
            f32x4 a = f32x4{0.f, 0.f, 0.f, 0.f};
            a = MM(qfr[0], kf[t][0], a);
            a = MM(qfr[1], kf[t][1], a);
            const int cb = (j >> 2) + 3 - grp;
            const int cr = jb >> 4;
            s16x4 rb4 = *(const s16x4*)&RBT[cb * 16 + grp * 4];
            s16x4 rr4 = *(const s16x4*)&RRT[cr * 16 + grp * 4];
            f32x4 pe;
            #pragma unroll
            for (int g = 0; g < 4; ++g) {
                const int ii = grp * 4 + g;
                const float gq = bf2f(RQ[ii * RQS + (j + 15 - ii)]);
                pe[g] = exp2f((a[g] + gq + bf2f(rb4[g]) + bf2f(rr4[g])) * SC);
            }
            p[t] = pe;
        }
        f32x4 rs = p[0];
        #pragma unroll
        for (int t = 1; t < 8; ++t) rs += p[t];
        #pragma unroll
        for (int m = 1; m < 16; m <<= 1)
            #pragma unroll
            for (int g = 0; g < 4; ++g)
                rs[g] += __shfl_xor(rs[g], m, 64);
        if (l15 == 0) {
            #pragma unroll
            for (int g = 0; g < 4; ++g)
                RSUM[(grp * 4 + g) * 8 + wid] = rs[g];
        }
        __syncthreads();
        #pragma unroll
        for (int g = 0; g < 4; ++g) {
            f32x4 s0 = *(const f32x4*)&RSUM[(grp * 4 + g) * 8];
            f32x4 s1 = *(const f32x4*)&RSUM[(grp * 4 + g) * 8 + 4];
            rinv[g] = 1.0f / (s0[0] + s0[1] + s0[2] + s0[3] + s1[0] + s1[1] + s1[2] + s1[3]);
        }
    } else {
        #pragma unroll
        for (int t = 0; t < 8; ++t)
            #pragma unroll
            for (int g = 0; g < 4; ++g)
                p[t][g] = bf2f(qfr[0][g]);
        #pragma unroll
        for (int g = 0; g < 4; ++g) rinv[g] = 1.0f;
    }

    // ---- V prefetch ----
    const int c = wid >> 1, kh = wid & 1;
    s16x8 vreg[16];
    if constexpr (PVx) {
        const short* vrow = vTH + (size_t)(c * 16 + l15) * 1024 + kh * 512 + grp * 8;
        #pragma unroll
        for (int kk = 0; kk < 16; ++kk)
            vreg[kk] = *(const s16x8*)(vrow + kk * 32);
    }

    // ---- loop 2: stage bf16 P ----
    #pragma unroll
    for (int t = 0; t < 8; ++t) {
        const int jb = wid * 128 + t * 16;
        #pragma unroll
        for (int g = 0; g < 4; ++g) {
            const int ii = grp * 4 + g;
            PS[ii * PSS + jb + l15] = f2bf(p[t][g] * rinv[g]);
        }
    }
    __syncthreads();

    auto attn_store = [&]() {
        const float* rbase_attn = attn + (size_t)(bh * 1024 + i0) * 1024;
        #pragma unroll
        for (int rr = 0; rr < 2; ++rr) {
            const int row = wid * 2 + rr;
            float* arow = (float*)rbase_attn + (size_t)row * 1024;
            #pragma unroll
            for (int pass = 0; pass < 4; ++pass) {
                const int col = pass * 256 + lane * 4;
                s16x4 v4 = *(const s16x4*)&PS[row * PSS + col];
                f32x4 o;
                o[0] = bf2f(v4[0]); o[1] = bf2f(v4[1]);
                o[2] = bf2f(v4[2]); o[3] = bf2f(v4[3]);
                if constexpr (AST) *(f32x4*)(arow + col) = o;
                else SINK4(o);
            }
        }
    };

    if constexpr (!LAST) attn_store();

    if constexpr (PVx) {
        f32x4 acc = f32x4{0.f, 0.f, 0.f, 0.f};
        const short* prow = PS + (size_t)l15 * PSS + kh * 512 + grp * 8;
        #pragma unroll
        for (int kk = 0; kk < 16; ++kk) {
            s16x8 af = *(const s16x8*)(prow + kk * 32);
            acc = MM(af, vreg[kk], acc);
        }
        #pragma unroll
        for (int g = 0; g < 4; ++g)
            PACC[(wid * 16 + grp * 4 + g) * 16 + l15] = acc[g];
        __syncthreads();
        if (wid < 4) {
            const int b = bh >> 3;
            #pragma unroll
            for (int g = 0; g < 4; ++g) {
                const int row = grp * 4 + g;
                const float v = PACC[((2 * wid) * 16 + row) * 16 + l15]
                              + PACC[((2 * wid + 1) * 16 + row) * 16 + l15];
                out[(size_t)(b * 1024 + i0 + row) * 512 + h * 64 + wid * 16 + l15] = v;
            }
        }
    }

    if constexpr (LAST) attn_store();   // stores in flight at endpgm; no barrier after
}

// ---------------------------------------------------------------------------
extern "C" void kernel_launch(void* const* d_in, const int* in_sizes, int n_in,
                              void* d_out, int out_size, void* d_ws, size_t ws_size,
                              hipStream_t stream)
{
    const float* query = (const float*)d_in[0];
    const float* key   = (const float*)d_in[1];
    const float* value = (const float*)d_in[2];
    const float* Wq = (const float*)d_in[3];
    const float* bq = (const float*)d_in[4];
    const float* Wk = (const float*)d_in[5];
    const float* bk = (const float*)d_in[6];
    const float* Wv = (const float*)d_in[7];
    const float* bv = (const float*)d_in[8];
    const float* Eq = (const float*)d_in[9];
    const float* Eb = (const float*)d_in[10];
    const float* Er = (const float*)d_in[11];

    float* out  = (float*)d_out;
    float* attn = out + (size_t)4 * 1024 * 512;

    short* qb     = (short*)d_ws;
    short* kb     = qb     + 2097152;
    short* vT     = kb     + 2097152;
    short* queryb = vT     + 2097152;
    short* keyb   = queryb + 2097152;
    short* valueb = keyb   + 2097152;
    short* Wqb    = valueb + 2097152;
    short* Wkb    = Wqb    + 262144;
    short* Wvb    = Wkb    + 262144;
    short* Eqb    = Wvb    + 262144;
    short* Ebb    = Eqb    + 1048064;
    short* Errb   = Ebb    + 261632;

    CvtArgs a;
    a.src[0] = query; a.dst[0] = queryb; a.n[0] = 2097152;
    a.src[1] = key;   a.dst[1] = keyb;   a.n[1] = 2097152;
    a.src[2] = value; a.dst[2] = valueb; a.n[2] = 2097152;
    a.src[3] = Wq;    a.dst[3] = Wqb;    a.n[3] = 262144;
    a.src[4] = Wk;    a.dst[4] = Wkb;    a.n[4] = 262144;
    a.src[5] = Wv;    a.dst[5] = Wvb;    a.n[5] = 262144;
    a.src[6] = Eq;    a.dst[6] = Eqb;    a.n[6] = 1048064;
    a.src[7] = Eb;    a.dst[7] = Ebb;    a.n[7] = 261632;
    a.src[8] = Er;    a.dst[8] = Errb;   a.n[8] = 65024;

    convert_kernel<<<dim3(256, 9), 256, 0, stream>>>(a);
    proj_kernel<<<1536, 256, 0, stream>>>(queryb, keyb, valueb,
                                          Wqb, bq, Wkb, bk, Wvb, bv, qb, kb, vT);

    // Ablation sequence; V6 (full, store-last) runs LAST -> correct final state.
    attn_ab<5><<<2048, 512, 0, stream>>>(Eqb, Ebb, Errb, qb, kb, vT, out, attn);
    attn_ab<4><<<2048, 512, 0, stream>>>(Eqb, Ebb, Errb, qb, kb, vT, out, attn);
    attn_ab<3><<<2048, 512, 0, stream>>>(Eqb, Ebb, Errb, qb, kb, vT, out, attn);
    attn_ab<2><<<2048, 512, 0, stream>>>(Eqb, Ebb, Errb, qb, kb, vT, out, attn);
    attn_ab<1><<<2048, 512, 0, stream>>>(Eqb, Ebb, Errb, qb, kb, vT, out, attn);
    attn_ab<0><<<2048, 512, 0, stream>>>(Eqb, Ebb, Errb, qb, kb, vT, out, attn);
    attn_ab<6><<<2048, 512, 0, stream>>>(Eqb, Ebb, Errb, qb, kb, vT, out, attn);
}

// Round 6
// 159.312 us; speedup vs baseline: 4.3886x; 4.3886x over previous
//
#include <hip/hip_runtime.h>

// Multihead self-attention with 3-scale relative positional embeddings.
// B=4, S=1024, D=512, H=8, HD=64.  Outputs: out (4,1024,512) f32, attn (4,8,1024,1024) f32.
//
// Skew algebra (verified round 1):
//   Srel_q[i,j]  = q[i] . Er_q[1023 + j - i]
//   Srel_b[i,j]  = q[i] . Er_b[255 + (j>>2) - (i>>2)]
//   Srel_r[i,j]  = q[i] . Er_r[63  + (j>>4) - (i>>4)]
//
// Round-6: persistent blocks. 256 blocks (1/CU), each owns a (b,h, 128-row
// chunk) and iterates 8 strips of 16 rows. K/V fragments register-resident
// across strips (loaded once); rel-tables double-buffered so strip s+1's
// Er-load+build overlaps strip s's softmax/PV; diagonal RQD table layout
// gives vectorized conflict-free gathers.

typedef float f32x4 __attribute__((ext_vector_type(4)));
typedef short s16x8 __attribute__((ext_vector_type(8)));
typedef short s16x4 __attribute__((ext_vector_type(4)));
typedef __bf16 bf16x8 __attribute__((ext_vector_type(8)));

static __device__ __forceinline__ short f2bf(float f) {
    return __builtin_bit_cast(short, (__bf16)f);
}
static __device__ __forceinline__ float bf2f(short s) {
    union { unsigned u; float f; } v;
    v.u = ((unsigned)(unsigned short)s) << 16;
    return v.f;
}
static __device__ __forceinline__ f32x4 MM(s16x8 a, s16x8 b, f32x4 c) {
    return __builtin_amdgcn_mfma_f32_16x16x32_bf16(
        __builtin_bit_cast(bf16x8, a), __builtin_bit_cast(bf16x8, b), c, 0, 0, 0);
}

// ---------------------------------------------------------------------------
// K0: one-shot f32 -> bf16 conversion of all reused operands.
// ---------------------------------------------------------------------------
struct CvtArgs {
    const float* src[9];
    short* dst[9];
    unsigned n[9];
};

__global__ __launch_bounds__(256) void convert_kernel(CvtArgs a) {
    const int ai = blockIdx.y;
    const unsigned n = a.n[ai];
    const float* __restrict__ s = a.src[ai];
    short* __restrict__ d = a.dst[ai];
    const unsigned stride = gridDim.x * 256 * 8;
    for (unsigned base = (blockIdx.x * 256 + threadIdx.x) * 8; base < n; base += stride) {
        f32x4 v0 = *(const f32x4*)(s + base);
        f32x4 v1 = *(const f32x4*)(s + base + 4);
        s16x8 o;
        o[0] = f2bf(v0[0]); o[1] = f2bf(v0[1]); o[2] = f2bf(v0[2]); o[3] = f2bf(v0[3]);
        o[4] = f2bf(v1[0]); o[5] = f2bf(v1[1]); o[6] = f2bf(v1[2]); o[7] = f2bf(v1[3]);
        *(s16x8*)(d + base) = o;
    }
}

// ---------------------------------------------------------------------------
// K1: QKV projections (bf16 in, bf16 out). One wave = 32x32 tile, 2x2 MFMA,
// 3-deep register pipeline over K.
// ---------------------------------------------------------------------------
__global__ __launch_bounds__(256, 2) void proj_kernel(
    const short* __restrict__ queryb, const short* __restrict__ keyb, const short* __restrict__ valueb,
    const short* __restrict__ Wqb, const float* __restrict__ bq,
    const short* __restrict__ Wkb, const float* __restrict__ bk,
    const short* __restrict__ Wvb, const float* __restrict__ bv,
    short* __restrict__ qb, short* __restrict__ kb, short* __restrict__ vT)
{
    const int tid = threadIdx.x;
    const int wid = tid >> 6, lane = tid & 63;
    const int l15 = lane & 15, grp = lane >> 4;
    const int gid = blockIdx.x * 4 + wid;
    const int z = gid >> 11;
    const int r = gid & 2047;

    const short *Am, *Bm;
    const float* bias;
    int a0, b0;
    if (z == 0)      { Am = queryb; Bm = Wqb;    bias = bq; a0 = (r >> 4) * 32; b0 = (r & 15) * 32; }
    else if (z == 1) { Am = keyb;   Bm = Wkb;    bias = bk; a0 = (r >> 4) * 32; b0 = (r & 15) * 32; }
    else             { Am = Wvb;    Bm = valueb; bias = bv; a0 = (r >> 7) * 32; b0 = (r & 127) * 32; }

    f32x4 acc[2][2];
    #pragma unroll
    for (int i = 0; i < 2; ++i)
        #pragma unroll
        for (int j = 0; j < 2; ++j)
            acc[i][j] = f32x4{0.f, 0.f, 0.f, 0.f};

    const short* arow0 = Am + (size_t)(a0 + l15) * 512 + grp * 8;
    const short* brow0 = Bm + (size_t)(b0 + l15) * 512 + grp * 8;

    s16x8 aA[2], bA[2], aB[2], bB[2], aC[2], bC[2];
    #pragma unroll
    for (int i = 0; i < 2; ++i) {
        aA[i] = *(const s16x8*)(arow0 + (size_t)i * 16 * 512);
        bA[i] = *(const s16x8*)(brow0 + (size_t)i * 16 * 512);
        aB[i] = *(const s16x8*)(arow0 + (size_t)i * 16 * 512 + 32);
        bB[i] = *(const s16x8*)(brow0 + (size_t)i * 16 * 512 + 32);
        aC[i] = *(const s16x8*)(arow0 + (size_t)i * 16 * 512 + 64);
        bC[i] = *(const s16x8*)(brow0 + (size_t)i * 16 * 512 + 64);
    }
    for (int kk = 0; kk < 512; kk += 32) {
        #pragma unroll
        for (int i = 0; i < 2; ++i)
            #pragma unroll
            for (int j = 0; j < 2; ++j)
                acc[i][j] = MM(aA[i], bA[j], acc[i][j]);
        #pragma unroll
        for (int i = 0; i < 2; ++i) { aA[i] = aB[i]; bA[i] = bB[i]; aB[i] = aC[i]; bB[i] = bC[i]; }
        const int kn = kk + 96;
        if (kn < 512) {
            #pragma unroll
            for (int i = 0; i < 2; ++i) {
                aC[i] = *(const s16x8*)(arow0 + (size_t)i * 16 * 512 + kn);
                bC[i] = *(const s16x8*)(brow0 + (size_t)i * 16 * 512 + kn);
            }
        }
    }

    if (z < 2) {
        short* dst = (z == 0) ? qb : kb;
        #pragma unroll
        for (int j = 0; j < 2; ++j) {
            const int n = b0 + j * 16 + l15;
            const float bval = bias[n];
            const int h = n >> 6, d = n & 63;
            #pragma unroll
            for (int i = 0; i < 2; ++i)
                #pragma unroll
                for (int g = 0; g < 4; ++g) {
                    const int m = a0 + i * 16 + grp * 4 + g;
                    const int bb = m >> 10, s = m & 1023;
                    dst[(size_t)((bb * 8 + h) * 1024 + s) * 64 + d] = f2bf(acc[i][j][g] + bval);
                }
        }
    } else {
        #pragma unroll
        for (int i = 0; i < 2; ++i)
            #pragma unroll
            for (int g = 0; g < 4; ++g) {
                const int n = a0 + i * 16 + grp * 4 + g;
                const float bval = bias[n];
                const int h = n >> 6, d = n & 63;
                #pragma unroll
                for (int j = 0; j < 2; ++j) {
                    const int m = b0 + j * 16 + l15;
                    const int bb = m >> 10, s = m & 1023;
                    vT[(size_t)((bb * 8 + h) * 64 + d) * 1024 + s] = f2bf(acc[i][j][g] + bval);
                }
            }
    }
}

// ---------------------------------------------------------------------------
// K2: persistent fused relative attention.
// Grid 256 x 512thr. Block = (b,h, 128-row chunk) -> 8 strips of 16 rows.
// LDS 119104B (1 block/CU):
//   RQD  x2: [1056][20] bf16 @ 0, 42240      (diagonal table RQD[j+15][ii];
//                                             PS[16][1032] overlays cur buf)
//   RBT  x2: [260][20] bf16  @ 84480, 94880
//   RRT  x2: [64][20]  bf16  @ 105280, 107840
//   RSUM [16][8] f32         @ 110400
//   PACC [128][16] f32       @ 110912
// ---------------------------------------------------------------------------
__global__ __launch_bounds__(512, 2) void attn_kernel(
    const short* __restrict__ Eqb, const short* __restrict__ Ebb, const short* __restrict__ Errb,
    const short* __restrict__ qb, const short* __restrict__ kb, const short* __restrict__ vT,
    float* __restrict__ out, float* __restrict__ attn)
{
    __shared__ __align__(16) char smem[119104];
    float* RSUM = (float*)(smem + 110400);
    float* PACC = (float*)(smem + 110912);
    const int PSS = 1032;

    const int tid = threadIdx.x;
    const int wid = tid >> 6, lane = tid & 63;
    const int l15 = lane & 15, grp = lane >> 4;

    // XCD-aware bijective swizzle: 256 blocks, XCD x owns data-bids 32x..32x+31
    // (= 4 whole bh -> ~2.5MB L2 working set per XCD).
    const int orig = blockIdx.x;
    const int bid = (orig & 7) * 32 + (orig >> 3);

    const int bh = bid >> 3;                 // b*8+h
    const int chunk = bid & 7;               // 128-row chunk
    const int h = bh & 7;
    const int b = bh >> 3;

    const short* EqH = Eqb  + (size_t)h * 2047 * 64;
    const short* EbH = Ebb  + (size_t)h * 511 * 64;
    const short* ErH = Errb + (size_t)h * 127 * 64;
    const short* qbH = qb + (size_t)bh * 1024 * 64;
    const short* kbH = kb + (size_t)bh * 1024 * 64;
    const short* vTH = vT + (size_t)bh * 64 * 1024;

    // ---- table builder (strip i0s -> buffer bb01) ----
    auto buildT = [&](int i0s, int bb01, s16x8 q0, s16x8 q1) {
        short* RQD = (short*)(smem + bb01 * 42240);
        short* RBT = (short*)(smem + 84480 + bb01 * 10400);
        short* RRT = (short*)(smem + 105280 + bb01 * 2560);
        const int qbase = 1008 - i0s;
        for (int cs = wid; cs < 65; cs += 8) {
            int erow = qbase + cs * 16 + l15; if (erow > 2046) erow = 2046;
            const short* ep = EqH + (size_t)erow * 64 + grp * 8;
            s16x8 e0 = *(const s16x8*)ep;
            s16x8 e1 = *(const s16x8*)(ep + 32);
            f32x4 a = f32x4{0.f, 0.f, 0.f, 0.f};
            a = MM(q0, e0, a);
            a = MM(q1, e1, a);
            const int cb0 = cs * 16 + l15;
            #pragma unroll
            for (int g = 0; g < 4; ++g) {
                const int ii = grp * 4 + g;
                RQD[(cb0 + ii) * 20 + ii] = f2bf(a[g]);   // diagonal: row d = c+ii
            }
        }
        const int bbase = 252 - (i0s >> 2);
        for (int cs = wid; cs < 17; cs += 8) {
            int erow = bbase + cs * 16 + l15; if (erow > 510) erow = 510;
            const short* ep = EbH + (size_t)erow * 64 + grp * 8;
            s16x8 e0 = *(const s16x8*)ep;
            s16x8 e1 = *(const s16x8*)(ep + 32);
            f32x4 a = f32x4{0.f, 0.f, 0.f, 0.f};
            a = MM(q0, e0, a);
            a = MM(q1, e1, a);
            const int c = cs * 16 + l15;
            if (c < 260) {
                #pragma unroll
                for (int g = 0; g < 4; ++g)
                    RBT[c * 20 + grp * 4 + g] = f2bf(a[g]);
            }
        }
        const int rbase = 63 - (i0s >> 4);
        if (wid < 4) {
            const int erow = rbase + wid * 16 + l15;
            const short* ep = ErH + (size_t)erow * 64 + grp * 8;
            s16x8 e0 = *(const s16x8*)ep;
            s16x8 e1 = *(const s16x8*)(ep + 32);
            f32x4 a = f32x4{0.f, 0.f, 0.f, 0.f};
            a = MM(q0, e0, a);
            a = MM(q1, e1, a);
            #pragma unroll
            for (int g = 0; g < 4; ++g)
                RRT[(wid * 16 + l15) * 20 + grp * 4 + g] = f2bf(a[g]);
        }
    };

    // ---- prologue: q(strip0), then K/V register-resident fragments ----
    const int i0_0 = chunk * 128;
    s16x8 qA0 = *(const s16x8*)(qbH + (size_t)(i0_0 + l15) * 64 + grp * 8);
    s16x8 qA1 = *(const s16x8*)(qbH + (size_t)(i0_0 + l15) * 64 + 32 + grp * 8);

    s16x8 kf[8][2];
    #pragma unroll
    for (int t = 0; t < 8; ++t) {
        const short* kp = kbH + (size_t)(wid * 128 + t * 16 + l15) * 64 + grp * 8;
        kf[t][0] = *(const s16x8*)kp;
        kf[t][1] = *(const s16x8*)(kp + 32);
    }
    const int cv = wid >> 1, kh = wid & 1;
    const short* vrow = vTH + (size_t)(cv * 16 + l15) * 1024 + kh * 512 + grp * 8;
    s16x8 vreg[16];
    #pragma unroll
    for (int kk = 0; kk < 16; ++kk)
        vreg[kk] = *(const s16x8*)(vrow + kk * 32);

    buildT(i0_0, 0, qA0, qA1);
    __syncthreads();

    const float SC = 0.125f * 1.4426950408889634f;   // 1/sqrt(64) * log2(e)

    #pragma unroll 2
    for (int s = 0; s < 8; ++s) {
        const int cur = s & 1;
        const int i0 = chunk * 128 + s * 16;
        short* RQDc = (short*)(smem + cur * 42240);
        short* RBTc = (short*)(smem + 84480 + cur * 10400);
        short* RRTc = (short*)(smem + 105280 + cur * 2560);
        short* PS   = (short*)(smem + cur * 42240);   // overlays RQDc (dead after loop1)

        // ---- a: QK^T + vector gathers + exp2 ----
        f32x4 p[8];
        #pragma unroll
        for (int t = 0; t < 8; ++t) {
            const int jb = wid * 128 + t * 16;
            const int j = jb + l15;
            f32x4 a = f32x4{0.f, 0.f, 0.f, 0.f};
            a = MM(qA0, kf[t][0], a);
            a = MM(qA1, kf[t][1], a);
            const int cb = (j >> 2) + 3 - grp;
            const int cr = wid * 8 + t;
            s16x4 gq4 = *(const s16x4*)&RQDc[(j + 15) * 20 + grp * 4];
            s16x4 rb4 = *(const s16x4*)&RBTc[cb * 20 + grp * 4];
            s16x4 rr4 = *(const s16x4*)&RRTc[cr * 20 + grp * 4];
            f32x4 pe;
            #pragma unroll
            for (int g = 0; g < 4; ++g)
                pe[g] = exp2f((a[g] + bf2f(gq4[g]) + bf2f(rb4[g]) + bf2f(rr4[g])) * SC);
            p[t] = pe;
        }

        // ---- b: prefetch next strip's q ----
        s16x8 qn0, qn1;
        if (s < 7) {
            qn0 = *(const s16x8*)(qbH + (size_t)(i0 + 16 + l15) * 64 + grp * 8);
            qn1 = *(const s16x8*)(qbH + (size_t)(i0 + 16 + l15) * 64 + 32 + grp * 8);
        }

        // ---- row sums ----
        f32x4 rs = p[0];
        #pragma unroll
        for (int t = 1; t < 8; ++t) rs += p[t];
        #pragma unroll
        for (int m = 1; m < 16; m <<= 1)
            #pragma unroll
            for (int g = 0; g < 4; ++g)
                rs[g] += __shfl_xor(rs[g], m, 64);
        if (l15 == 0) {
            #pragma unroll
            for (int g = 0; g < 4; ++g)
                RSUM[(grp * 4 + g) * 8 + wid] = rs[g];
        }
        __syncthreads();                       // bar 1: RSUM ready; other T buf free

        // ---- d: per-lane 1/rowsum ----
        float rinv[4];
        #pragma unroll
        for (int g = 0; g < 4; ++g) {
            f32x4 s0 = *(const f32x4*)&RSUM[(grp * 4 + g) * 8];
            f32x4 s1 = *(const f32x4*)&RSUM[(grp * 4 + g) * 8 + 4];
            rinv[g] = 1.0f / (s0[0] + s0[1] + s0[2] + s0[3] + s1[0] + s1[1] + s1[2] + s1[3]);
        }

        // ---- e: build next strip's tables (Er latency hides here) ----
        if (s < 7) buildT(i0 + 16, cur ^ 1, qn0, qn1);

        // ---- f: normalize + stage bf16 P (overlay of RQDc, now dead) ----
        #pragma unroll
        for (int t = 0; t < 8; ++t) {
            const int jb = wid * 128 + t * 16;
            #pragma unroll
            for (int g = 0; g < 4; ++g)
                PS[(grp * 4 + g) * PSS + jb + l15] = f2bf(p[t][g] * rinv[g]);
        }
        __syncthreads();                       // bar 2: PS visible

        // ---- h: coalesced attn store + PV from register V ----
        {
            float* abase = attn + (size_t)(bh * 1024 + i0) * 1024;
            #pragma unroll
            for (int rr = 0; rr < 2; ++rr) {
                const int row = wid * 2 + rr;
                float* arow = abase + (size_t)row * 1024;
                #pragma unroll
                for (int pass = 0; pass < 4; ++pass) {
                    const int col = pass * 256 + lane * 4;
                    s16x4 v4 = *(const s16x4*)&PS[row * PSS + col];
                    f32x4 o;
                    o[0] = bf2f(v4[0]); o[1] = bf2f(v4[1]);
                    o[2] = bf2f(v4[2]); o[3] = bf2f(v4[3]);
                    *(f32x4*)(arow + col) = o;
                }
            }
        }
        {
            f32x4 acc = f32x4{0.f, 0.f, 0.f, 0.f};
            const short* prow = PS + (size_t)l15 * PSS + kh * 512 + grp * 8;
            #pragma unroll
            for (int kk = 0; kk < 16; ++kk) {
                s16x8 af = *(const s16x8*)(prow + kk * 32);
                acc = MM(af, vreg[kk], acc);
            }
            #pragma unroll
            for (int g = 0; g < 4; ++g)
                PACC[(wid * 16 + grp * 4 + g) * 16 + l15] = acc[g];
        }
        __syncthreads();                       // bar 3: PACC complete

        // ---- epilogue: split-K reduce + out store ----
        if (wid < 4) {
            #pragma unroll
            for (int g = 0; g < 4; ++g) {
                const int row = grp * 4 + g;
                const float v = PACC[((2 * wid) * 16 + row) * 16 + l15]
                              + PACC[((2 * wid + 1) * 16 + row) * 16 + l15];
                out[(size_t)(b * 1024 + i0 + row) * 512 + h * 64 + wid * 16 + l15] = v;
            }
        }

        if (s < 7) { qA0 = qn0; qA1 = qn1; }
    }
}

// ---------------------------------------------------------------------------
extern "C" void kernel_launch(void* const* d_in, const int* in_sizes, int n_in,
                              void* d_out, int out_size, void* d_ws, size_t ws_size,
                              hipStream_t stream)
{
    const float* query = (const float*)d_in[0];
    const float* key   = (const float*)d_in[1];
    const float* value = (const float*)d_in[2];
    const float* Wq = (const float*)d_in[3];
    const float* bq = (const float*)d_in[4];
    const float* Wk = (const float*)d_in[5];
    const float* bk = (const float*)d_in[6];
    const float* Wv = (const float*)d_in[7];
    const float* bv = (const float*)d_in[8];
    const float* Eq = (const float*)d_in[9];
    const float* Eb = (const float*)d_in[10];
    const float* Er = (const float*)d_in[11];

    float* out  = (float*)d_out;
    float* attn = out + (size_t)4 * 1024 * 512;

    short* qb     = (short*)d_ws;
    short* kb     = qb     + 2097152;
    short* vT     = kb     + 2097152;
    short* queryb = vT     + 2097152;
    short* keyb   = queryb + 2097152;
    short* valueb = keyb   + 2097152;
    short* Wqb    = valueb + 2097152;
    short* Wkb    = Wqb    + 262144;
    short* Wvb    = Wkb    + 262144;
    short* Eqb    = Wvb    + 262144;
    short* Ebb    = Eqb    + 1048064;   // 8*2047*64
    short* Errb   = Ebb    + 261632;    // 8*511*64

    CvtArgs a;
    a.src[0] = query; a.dst[0] = queryb; a.n[0] = 2097152;
    a.src[1] = key;   a.dst[1] = keyb;   a.n[1] = 2097152;
    a.src[2] = value; a.dst[2] = valueb; a.n[2] = 2097152;
    a.src[3] = Wq;    a.dst[3] = Wqb;    a.n[3] = 262144;
    a.src[4] = Wk;    a.dst[4] = Wkb;    a.n[4] = 262144;
    a.src[5] = Wv;    a.dst[5] = Wvb;    a.n[5] = 262144;
    a.src[6] = Eq;    a.dst[6] = Eqb;    a.n[6] = 1048064;
    a.src[7] = Eb;    a.dst[7] = Ebb;    a.n[7] = 261632;
    a.src[8] = Er;    a.dst[8] = Errb;   a.n[8] = 65024;

    convert_kernel<<<dim3(256, 9), 256, 0, stream>>>(a);
    proj_kernel<<<1536, 256, 0, stream>>>(queryb, keyb, valueb,
                                          Wqb, bq, Wkb, bk, Wvb, bv, qb, kb, vT);
    attn_kernel<<<256, 512, 0, stream>>>(Eqb, Ebb, Errb, qb, kb, vT, out, attn);
}

// Round 7
// 129.500 us; speedup vs baseline: 5.3990x; 1.2302x over previous
//
#include <hip/hip_runtime.h>

// Multihead self-attention with 3-scale relative positional embeddings.
// B=4, S=1024, D=512, H=8, HD=64.  Outputs: out (4,1024,512) f32, attn (4,8,1024,1024) f32.
//
// Skew algebra (verified round 1):
//   Srel_q[i,j]  = q[i] . Er_q[1023 + j - i]
//   Srel_b[i,j]  = q[i] . Er_b[255 + (j>>2) - (i>>2)]
//   Srel_r[i,j]  = q[i] . Er_r[63  + (j>>4) - (i>>4)]
//
// Round-7: swapped-operand QK^T (P row-per-lane) -> attn stored from regs,
// vector PS staging, deferred normalization, shifted tables for aligned b64
// gathers, 2 barriers/strip, loop-carried register pins for K/V residency.

typedef float f32x4 __attribute__((ext_vector_type(4)));
typedef short s16x8 __attribute__((ext_vector_type(8)));
typedef short s16x4 __attribute__((ext_vector_type(4)));
typedef __bf16 bf16x8 __attribute__((ext_vector_type(8)));

static __device__ __forceinline__ short f2bf(float f) {
    return __builtin_bit_cast(short, (__bf16)f);
}
static __device__ __forceinline__ float bf2f(short s) {
    union { unsigned u; float f; } v;
    v.u = ((unsigned)(unsigned short)s) << 16;
    return v.f;
}
static __device__ __forceinline__ f32x4 MM(s16x8 a, s16x8 b, f32x4 c) {
    return __builtin_amdgcn_mfma_f32_16x16x32_bf16(
        __builtin_bit_cast(bf16x8, a), __builtin_bit_cast(bf16x8, b), c, 0, 0, 0);
}
#define KEEP(x) asm volatile("" : "+v"(x))

// ---------------------------------------------------------------------------
// K0: one-shot f32 -> bf16 conversion of all reused operands.
// ---------------------------------------------------------------------------
struct CvtArgs {
    const float* src[9];
    short* dst[9];
    unsigned n[9];
};

__global__ __launch_bounds__(256) void convert_kernel(CvtArgs a) {
    const int ai = blockIdx.y;
    const unsigned n = a.n[ai];
    const float* __restrict__ s = a.src[ai];
    short* __restrict__ d = a.dst[ai];
    const unsigned stride = gridDim.x * 256 * 8;
    for (unsigned base = (blockIdx.x * 256 + threadIdx.x) * 8; base < n; base += stride) {
        f32x4 v0 = *(const f32x4*)(s + base);
        f32x4 v1 = *(const f32x4*)(s + base + 4);
        s16x8 o;
        o[0] = f2bf(v0[0]); o[1] = f2bf(v0[1]); o[2] = f2bf(v0[2]); o[3] = f2bf(v0[3]);
        o[4] = f2bf(v1[0]); o[5] = f2bf(v1[1]); o[6] = f2bf(v1[2]); o[7] = f2bf(v1[3]);
        *(s16x8*)(d + base) = o;
    }
}

// ---------------------------------------------------------------------------
// K1: QKV projections, 64x64 wave tiles, swapped operands so all stores are
// vector b64.  768 blocks x 128 thr (2 waves).  wave gid in 0..1535:
//   z<2 (q,k): A = W (M=512 feat), B = data (N=4096 rows) -> D[feat][row]
//              store qb/kb[(bh,s,d)] packed over feat (4 consecutive d).
//   z=2 (v):   A = value (M=4096 rows), B = Wv (N=512 feat) -> D[row][feat]
//              store vT[(bh,d,s)] packed over rows (4 consecutive s).
// ---------------------------------------------------------------------------
__global__ __launch_bounds__(128, 2) void proj_kernel(
    const short* __restrict__ queryb, const short* __restrict__ keyb, const short* __restrict__ valueb,
    const short* __restrict__ Wqb, const float* __restrict__ bq,
    const short* __restrict__ Wkb, const float* __restrict__ bk,
    const short* __restrict__ Wvb, const float* __restrict__ bv,
    short* __restrict__ qb, short* __restrict__ kb, short* __restrict__ vT)
{
    const int tid = threadIdx.x;
    const int wid = tid >> 6, lane = tid & 63;
    const int l15 = lane & 15, grp = lane >> 4;
    const int gid = blockIdx.x * 2 + wid;     // 0..1535
    const int z = gid >> 9;                   // 0,1,2
    const int r = gid & 511;

    const short *Am, *Bm;
    const float* bias;
    int a0, b0;
    if (z == 0)      { Am = Wqb;    Bm = queryb; bias = bq; a0 = (r >> 6) * 64; b0 = (r & 63) * 64; }
    else if (z == 1) { Am = Wkb;    Bm = keyb;   bias = bk; a0 = (r >> 6) * 64; b0 = (r & 63) * 64; }
    else             { Am = valueb; Bm = Wvb;    bias = bv; a0 = (r >> 3) * 64; b0 = (r & 7) * 64; }

    f32x4 acc[4][4];
    #pragma unroll
    for (int i = 0; i < 4; ++i)
        #pragma unroll
        for (int j = 0; j < 4; ++j)
            acc[i][j] = f32x4{0.f, 0.f, 0.f, 0.f};

    const short* arow0 = Am + (size_t)(a0 + l15) * 512 + grp * 8;
    const short* brow0 = Bm + (size_t)(b0 + l15) * 512 + grp * 8;

    s16x8 aA[4], bA[4], aB[4], bB[4];
    #pragma unroll
    for (int i = 0; i < 4; ++i) {
        aA[i] = *(const s16x8*)(arow0 + (size_t)i * 16 * 512);
        bA[i] = *(const s16x8*)(brow0 + (size_t)i * 16 * 512);
    }
    for (int kk = 0; kk < 512; kk += 32) {
        const int kn = kk + 32;
        if (kn < 512) {
            #pragma unroll
            for (int i = 0; i < 4; ++i) {
                aB[i] = *(const s16x8*)(arow0 + (size_t)i * 16 * 512 + kn);
                bB[i] = *(const s16x8*)(brow0 + (size_t)i * 16 * 512 + kn);
            }
        }
        #pragma unroll
        for (int i = 0; i < 4; ++i)
            #pragma unroll
            for (int j = 0; j < 4; ++j)
                acc[i][j] = MM(aA[i], bA[j], acc[i][j]);
        #pragma unroll
        for (int i = 0; i < 4; ++i) { aA[i] = aB[i]; bA[i] = bB[i]; }
    }

    if (z < 2) {
        // D[m = feat f][n = data row s]; pack 4 consecutive feats (g).
        short* dst = (z == 0) ? qb : kb;
        #pragma unroll
        for (int i = 0; i < 4; ++i) {
            const int f0 = a0 + i * 16 + grp * 4;          // 4-aligned feature base
            const f32x4 bv4 = *(const f32x4*)&bias[f0];
            const int h = f0 >> 6, d0 = f0 & 63;
            #pragma unroll
            for (int j = 0; j < 4; ++j) {
                const int srow = b0 + j * 16 + l15;        // global data row
                const int bb = srow >> 10, sl = srow & 1023;
                s16x4 o;
                #pragma unroll
                for (int g = 0; g < 4; ++g)
                    o[g] = f2bf(acc[i][j][g] + bv4[g]);
                *(s16x4*)&dst[(size_t)((bb * 8 + h) * 1024 + sl) * 64 + d0] = o;
            }
        }
    } else {
        // D[m = data row s][n = feat]; pack 4 consecutive rows (g).
        #pragma unroll
        for (int j = 0; j < 4; ++j) {
            const int n = b0 + j * 16 + l15;               // feature
            const float bval = bias[n];
            const int h = n >> 6, d = n & 63;
            #pragma unroll
            for (int i = 0; i < 4; ++i) {
                const int s0 = a0 + i * 16 + grp * 4;      // 4 consecutive rows
                const int bb = s0 >> 10, sl = s0 & 1023;
                s16x4 o;
                #pragma unroll
                for (int g = 0; g < 4; ++g)
                    o[g] = f2bf(acc[i][j][g] + bval);
                *(s16x4*)&vT[(size_t)((bb * 8 + h) * 64 + d) * 1024 + sl] = o;
            }
        }
    }
}

// ---------------------------------------------------------------------------
// K2: persistent fused relative attention, swapped-operand layout.
// Grid 256 x 512thr; block = (b,h, 128-row chunk), 8 strips of 16 rows.
// Thread (wid,grp,l15) holds P[i=l15][j = wid*128 + t*16 + grp*4 + g].
// LDS 155008B:
//   RQ2 x2 [16][1028] bf16 @ 0 / 32896      (row-shifted: RQ2[i][j])
//   RB2 x2 [16][260]  bf16 @ 65792 / 74112  (RB2[i][j>>2])
//   RR2 x2 [16][68]   bf16 @ 82432 / 84608  (RR2[i][j>>4])
//   PS      [16][1028] bf16 @ 86784          (XOR-swizzled cols, unnormalized P)
//   PACC    [8][16][68] f32 @ 119680
//   RSUM x2 [16][8] f32     @ 154496 / 154752
// ---------------------------------------------------------------------------
__global__ __launch_bounds__(512, 2) void attn_kernel(
    const short* __restrict__ Eqb, const short* __restrict__ Ebb, const short* __restrict__ Errb,
    const short* __restrict__ qb, const short* __restrict__ kb, const short* __restrict__ vT,
    float* __restrict__ out, float* __restrict__ attn)
{
    __shared__ __align__(16) char smem[155008];
    short* PS   = (short*)(smem + 86784);
    float* PACC = (float*)(smem + 119680);

    const int tid = threadIdx.x;
    const int wid = tid >> 6, lane = tid & 63;
    const int l15 = lane & 15, grp = lane >> 4;

    // XCD-aware bijective swizzle (256 blocks, %8==0): XCD x -> bids 32x..32x+31.
    const int orig = blockIdx.x;
    const int bid = (orig & 7) * 32 + (orig >> 3);

    const int bh = bid >> 3;                 // b*8+h
    const int chunk = bid & 7;               // 128-row chunk
    const int h = bh & 7;
    const int b = bh >> 3;

    const short* EqH = Eqb  + (size_t)h * 2047 * 64;
    const short* EbH = Ebb  + (size_t)h * 511 * 64;
    const short* ErH = Errb + (size_t)h * 127 * 64;
    const short* qbH = qb + (size_t)bh * 1024 * 64;
    const short* kbH = kb + (size_t)bh * 1024 * 64;
    const short* vTH = vT + (size_t)bh * 64 * 1024;

    // ---- table builder: strip at i0s -> buffer bb01 (uses that strip's q) ----
    auto buildT = [&](int i0s, int bb01, s16x8 q0, s16x8 q1) {
        short* RQ2 = (short*)(smem + bb01 * 32896);
        short* RB2 = (short*)(smem + 65792 + bb01 * 8320);
        short* RR2 = (short*)(smem + 82432 + bb01 * 2176);
        const int qbase = 1008 - i0s;
        for (int cs = wid; cs < 65; cs += 8) {
            const int c = cs * 16 + l15;
            int erow = qbase + c; if (erow > 2046) erow = 2046;
            const short* ep = EqH + (size_t)erow * 64 + grp * 8;
            s16x8 e0 = *(const s16x8*)ep;
            s16x8 e1 = *(const s16x8*)(ep + 32);
            f32x4 a = f32x4{0.f, 0.f, 0.f, 0.f};
            a = MM(q0, e0, a);
            a = MM(q1, e1, a);
            #pragma unroll
            for (int g = 0; g < 4; ++g) {
                const int ii = grp * 4 + g;
                const int j = c - 15 + ii;
                if (j >= 0 && j < 1024) RQ2[ii * 1028 + j] = f2bf(a[g]);
            }
        }
        const int bbase = 252 - (i0s >> 2);
        for (int cs = wid; cs < 17; cs += 8) {
            const int c = cs * 16 + l15;
            int erow = bbase + c; if (erow > 510) erow = 510;
            const short* ep = EbH + (size_t)erow * 64 + grp * 8;
            s16x8 e0 = *(const s16x8*)ep;
            s16x8 e1 = *(const s16x8*)(ep + 32);
            f32x4 a = f32x4{0.f, 0.f, 0.f, 0.f};
            a = MM(q0, e0, a);
            a = MM(q1, e1, a);
            const int jq = c - 3 + grp;          // (ii>>2) == grp
            if (jq >= 0 && jq < 256) {
                #pragma unroll
                for (int g = 0; g < 4; ++g)
                    RB2[(grp * 4 + g) * 260 + jq] = f2bf(a[g]);
            }
        }
        const int rbase = 63 - (i0s >> 4);
        if (wid < 4) {
            const int c = wid * 16 + l15;        // 0..63
            const short* ep = ErH + (size_t)(rbase + c) * 64 + grp * 8;
            s16x8 e0 = *(const s16x8*)ep;
            s16x8 e1 = *(const s16x8*)(ep + 32);
            f32x4 a = f32x4{0.f, 0.f, 0.f, 0.f};
            a = MM(q0, e0, a);
            a = MM(q1, e1, a);
            #pragma unroll
            for (int g = 0; g < 4; ++g)
                RR2[(grp * 4 + g) * 68 + c] = f2bf(a[g]);
        }
    };

    // ---- prologue: q(strip0), K fragments (A-operand), V fragments ----
    const int i00 = chunk * 128;
    s16x8 qA0 = *(const s16x8*)(qbH + (size_t)(i00 + l15) * 64 + grp * 8);
    s16x8 qA1 = *(const s16x8*)(qbH + (size_t)(i00 + l15) * 64 + 32 + grp * 8);

    s16x8 kf[8][2];
    #pragma unroll
    for (int t = 0; t < 8; ++t) {
        const short* kp = kbH + (size_t)(wid * 128 + t * 16 + l15) * 64 + grp * 8;
        kf[t][0] = *(const s16x8*)kp;
        kf[t][1] = *(const s16x8*)(kp + 32);
    }
    // vreg[dvt*4+kc] = vT[dvt*16+l15][wid*128 + kc*32 + grp*8 ..]
    s16x8 vreg[16];
    #pragma unroll
    for (int dvt = 0; dvt < 4; ++dvt)
        #pragma unroll
        for (int kc = 0; kc < 4; ++kc)
            vreg[dvt * 4 + kc] = *(const s16x8*)(vTH + (size_t)(dvt * 16 + l15) * 1024
                                                 + wid * 128 + kc * 32 + grp * 8);

    buildT(i00, 0, qA0, qA1);
    __syncthreads();

    const float SC = 0.125f * 1.4426950408889634f;   // 1/sqrt(64) * log2(e)
    const int swz = (l15 & 3) << 5;                  // PS col XOR swizzle

    for (int s = 0; s < 8; ++s) {
        // loop-carried pins: forbid rematerializing kf/vreg loads per strip
        #pragma unroll
        for (int t = 0; t < 8; ++t) { KEEP(kf[t][0]); KEEP(kf[t][1]); }
        #pragma unroll
        for (int z = 0; z < 16; ++z) KEEP(vreg[z]);

        const int cur = s & 1;
        const int i0 = chunk * 128 + s * 16;
        short* RQ2c = (short*)(smem + cur * 32896);
        short* RB2c = (short*)(smem + 65792 + cur * 8320);
        short* RR2c = (short*)(smem + 82432 + cur * 2176);
        float* RSUMc = (float*)(smem + 154496 + cur * 256);

        // prefetch next strip's q (feeds buildT after BAR1)
        s16x8 qn0, qn1;
        if (s < 7) {
            qn0 = *(const s16x8*)(qbH + (size_t)(i0 + 16 + l15) * 64 + grp * 8);
            qn1 = *(const s16x8*)(qbH + (size_t)(i0 + 16 + l15) * 64 + 32 + grp * 8);
        }

        // ---- QK^T (swapped) + gathers + exp2 -> p (unnormalized) ----
        f32x4 p[8];
        #pragma unroll
        for (int t = 0; t < 8; ++t) {
            f32x4 a = f32x4{0.f, 0.f, 0.f, 0.f};
            a = MM(kf[t][0], qA0, a);
            a = MM(kf[t][1], qA1, a);
            const int jb2 = wid * 128 + t * 16 + grp * 4;
            s16x4 gq4 = *(const s16x4*)&RQ2c[l15 * 1028 + jb2];
            const float rb = bf2f(RB2c[l15 * 260 + wid * 32 + t * 4 + grp]);
            const float rr = bf2f(RR2c[l15 * 68 + wid * 8 + t]);
            const float add = rb + rr;
            f32x4 pe;
            #pragma unroll
            for (int g = 0; g < 4; ++g)
                pe[g] = exp2f((a[g] + bf2f(gq4[g]) + add) * SC);
            p[t] = pe;
        }

        // ---- in-thread row partial + cross-grp shuffle + RSUM ----
        float part = 0.f;
        #pragma unroll
        for (int t = 0; t < 8; ++t)
            #pragma unroll
            for (int g = 0; g < 4; ++g)
                part += p[t][g];
        part += __shfl_xor(part, 16, 64);
        part += __shfl_xor(part, 32, 64);
        if (lane < 16) RSUMc[lane * 8 + wid] = part;   // wave partial for row l15

        // ---- stage unnormalized bf16 P (vector b64, swizzled cols) ----
        #pragma unroll
        for (int t = 0; t < 8; ++t) {
            const int col = (wid * 128 + t * 16 + grp * 4) ^ swz;
            s16x4 o;
            #pragma unroll
            for (int g = 0; g < 4; ++g) o[g] = f2bf(p[t][g]);
            *(s16x4*)&PS[l15 * 1028 + col] = o;
        }
        __syncthreads();                               // BAR1: PS + RSUM ready

        // ---- rinv for this thread's row (l15) ----
        float rinv;
        {
            f32x4 s0 = *(const f32x4*)&RSUMc[l15 * 8];
            f32x4 s1 = *(const f32x4*)&RSUMc[l15 * 8 + 4];
            rinv = 1.0f / (s0[0] + s0[1] + s0[2] + s0[3] + s1[0] + s1[1] + s1[2] + s1[3]);
        }

        // ---- build next strip's tables (overlaps PV) ----
        if (s < 7) buildT(i0 + 16, cur ^ 1, qn0, qn1);

        // ---- PV: O_partial[i][dv] over this wave's 128 k-cols ----
        f32x4 acc[4];
        #pragma unroll
        for (int dvt = 0; dvt < 4; ++dvt) acc[dvt] = f32x4{0.f, 0.f, 0.f, 0.f};
        #pragma unroll
        for (int kc = 0; kc < 4; ++kc) {
            const int col = (wid * 128 + kc * 32 + grp * 8) ^ swz;
            s16x8 bfrag = *(const s16x8*)&PS[l15 * 1028 + col];
            #pragma unroll
            for (int dvt = 0; dvt < 4; ++dvt)
                acc[dvt] = MM(vreg[dvt * 4 + kc], bfrag, acc[dvt]);
        }
        #pragma unroll
        for (int dvt = 0; dvt < 4; ++dvt)
            *(f32x4*)&PACC[(wid * 16 + l15) * 68 + dvt * 16 + grp * 4] = acc[dvt];
        __syncthreads();                               // BAR2: PACC + tables built

        // ---- out-reduce (waves 0-3): sum 8 wave-partials, scale by rinv ----
        if (tid < 256) {
            const int i = tid >> 4, dvq = tid & 15;
            f32x4 o = f32x4{0.f, 0.f, 0.f, 0.f};
            #pragma unroll
            for (int w = 0; w < 8; ++w)
                o += *(const f32x4*)&PACC[(w * 16 + i) * 68 + dvq * 4];
            f32x4 s0 = *(const f32x4*)&RSUMc[i * 8];
            f32x4 s1 = *(const f32x4*)&RSUMc[i * 8 + 4];
            const float ri = 1.0f / (s0[0] + s0[1] + s0[2] + s0[3] + s1[0] + s1[1] + s1[2] + s1[3]);
            o *= ri;
            *(f32x4*)&out[(size_t)(b * 1024 + i0 + i) * 512 + h * 64 + dvq * 4] = o;
        }

        // ---- attn store straight from registers (drains under next strip) ----
        {
            float* arow = attn + (size_t)(bh * 1024 + i0 + l15) * 1024;
            #pragma unroll
            for (int t = 0; t < 8; ++t) {
                f32x4 o = p[t] * rinv;
                *(f32x4*)&arow[wid * 128 + t * 16 + grp * 4] = o;
            }
        }

        if (s < 7) { qA0 = qn0; qA1 = qn1; }
    }
}

// ---------------------------------------------------------------------------
extern "C" void kernel_launch(void* const* d_in, const int* in_sizes, int n_in,
                              void* d_out, int out_size, void* d_ws, size_t ws_size,
                              hipStream_t stream)
{
    const float* query = (const float*)d_in[0];
    const float* key   = (const float*)d_in[1];
    const float* value = (const float*)d_in[2];
    const float* Wq = (const float*)d_in[3];
    const float* bq = (const float*)d_in[4];
    const float* Wk = (const float*)d_in[5];
    const float* bk = (const float*)d_in[6];
    const float* Wv = (const float*)d_in[7];
    const float* bv = (const float*)d_in[8];
    const float* Eq = (const float*)d_in[9];
    const float* Eb = (const float*)d_in[10];
    const float* Er = (const float*)d_in[11];

    float* out  = (float*)d_out;
    float* attn = out + (size_t)4 * 1024 * 512;

    short* qb     = (short*)d_ws;
    short* kb     = qb     + 2097152;
    short* vT     = kb     + 2097152;
    short* queryb = vT     + 2097152;
    short* keyb   = queryb + 2097152;
    short* valueb = keyb   + 2097152;
    short* Wqb    = valueb + 2097152;
    short* Wkb    = Wqb    + 262144;
    short* Wvb    = Wkb    + 262144;
    short* Eqb    = Wvb    + 262144;
    short* Ebb    = Eqb    + 1048064;   // 8*2047*64
    short* Errb   = Ebb    + 261632;    // 8*511*64

    CvtArgs a;
    a.src[0] = query; a.dst[0] = queryb; a.n[0] = 2097152;
    a.src[1] = key;   a.dst[1] = keyb;   a.n[1] = 2097152;
    a.src[2] = value; a.dst[2] = valueb; a.n[2] = 2097152;
    a.src[3] = Wq;    a.dst[3] = Wqb;    a.n[3] = 262144;
    a.src[4] = Wk;    a.dst[4] = Wkb;    a.n[4] = 262144;
    a.src[5] = Wv;    a.dst[5] = Wvb;    a.n[5] = 262144;
    a.src[6] = Eq;    a.dst[6] = Eqb;    a.n[6] = 1048064;
    a.src[7] = Eb;    a.dst[7] = Ebb;    a.n[7] = 261632;
    a.src[8] = Er;    a.dst[8] = Errb;   a.n[8] = 65024;

    convert_kernel<<<dim3(1024, 9), 256, 0, stream>>>(a);
    proj_kernel<<<768, 128, 0, stream>>>(queryb, keyb, valueb,
                                         Wqb, bq, Wkb, bk, Wvb, bv, qb, kb, vT);
    attn_kernel<<<256, 512, 0, stream>>>(Eqb, Ebb, Errb, qb, kb, vT, out, attn);
}